// Round 12
// baseline (1298.321 us; speedup 1.0000x reference)
//
#include <hip/hip_runtime.h>
#include <cstdint>

#define MN 50000
#define EN 800000
#define HID 320
#define HEADS 4
#define HDIM 80
#define NEG_SLOPE 0.2f

typedef __attribute__((ext_vector_type(4))) float f32x4;
typedef __attribute__((ext_vector_type(8))) short short8v;

__device__ __forceinline__ unsigned short f2bf(float f){
  unsigned u = __float_as_uint(f);
  return (unsigned short)((u + 0x7fffu + ((u >> 16) & 1u)) >> 16);  // RNE
}
__device__ __forceinline__ float bf2f(unsigned short s){
  return __uint_as_float(((unsigned)s) << 16);
}

// ======================= CSR build (counting sort by dst) =======================
__global__ void hist_kernel(const int* __restrict__ dst, int* __restrict__ hist, int E) {
  int e = blockIdx.x * 256 + threadIdx.x;
  if (e < E) atomicAdd(&hist[dst[e]], 1);
}

__global__ __launch_bounds__(1024) void scan_kernel(const int* __restrict__ hist,
                                                    int* __restrict__ row_off, int n) {
  __shared__ int part[1024];
  int t = threadIdx.x;
  int chunk = (n + 1023) >> 10;
  int beg = t * chunk, end = beg + chunk;
  if (end > n) end = n;
  if (beg > n) beg = n;
  int s = 0;
  for (int i = beg; i < end; i++) s += hist[i];
  part[t] = s;
  __syncthreads();
  for (int off = 1; off < 1024; off <<= 1) {
    int v = (t >= off) ? part[t - off] : 0;
    __syncthreads();
    if (t >= off) part[t] += v;
    __syncthreads();
  }
  int run = (t > 0) ? part[t - 1] : 0;
  for (int i = beg; i < end; i++) { row_off[i] = run; run += hist[i]; }
  if (t == 0) row_off[n] = part[1023];
}

__global__ void scatter_kernel(const int* __restrict__ src, const int* __restrict__ dst,
                               const int* __restrict__ row_off, int* __restrict__ cur,
                               int* __restrict__ csr_src, int E) {
  int e = blockIdx.x * 256 + threadIdx.x;
  if (e < E) {
    int d = dst[e];
    int p = atomicAdd(&cur[d], 1);
    csr_src[row_off[d] + p] = src[e];
  }
}

// ======================= weight prep: transpose + bf16x2 split + chunk swizzle ==
__global__ void wprep(const float* __restrict__ W, unsigned short* __restrict__ dst,
                      int K, int Nsz, int total) {
  int idx = blockIdx.x * 256 + threadIdx.x;
  if (idx >= total) return;
  int j = idx & 7;
  int c1 = (idx >> 3) & 3;
  int rest = idx >> 5;
  int col = rest % Nsz;
  int kt = rest / Nsz;
  int chunk = c1 ^ ((col >> 1) & 3);
  int kp = kt * 32 + chunk * 8 + j;
  int seg = kp / K;
  int k = kp - seg * K;
  float v = W[(size_t)k * Nsz + col];
  unsigned short h = f2bf(v);
  unsigned short o = (seg == 2) ? f2bf(v - bf2f(h)) : h;
  dst[(size_t)kt * Nsz * 32 + (size_t)col * 32 + c1 * 8 + j] = o;
}

// ======================= stacked-K bf16 MFMA GEMM ==============================
// A staged via LDS (reg-staged, 80B pitch); B read DIRECTLY from global (L2-hit,
// per-lane 16B fragments, double-buffered in registers - no LDS, no barrier drain).
// MODE: 0 = f32 raw ; 1 = f32 bias+relu ; 2 = split bias+relu ;
//       3 = split bias+BN+relu ; 4 = split raw
template<int CW, bool SRCF32, int SEGT, int NPASS, int MODE>
__global__ __launch_bounds__(128 * CW) void mfma_gemm(
    const char* __restrict__ A1, const char* __restrict__ A2,
    const char* __restrict__ Wq,
    const float* __restrict__ bias, const float* __restrict__ gamma,
    const float* __restrict__ beta, void* __restrict__ outp, int M)
{
  static_assert(!SRCF32 || CW == 4, "");
  constexpr int TPB = 128 * CW;
  constexpr int N = CW * 80;
  constexpr int NT = NPASS * 3 * SEGT;      // even for all instantiations
  constexpr int TILEB = N * 64;
  constexpr int AIT = (384 + TPB - 1) / TPB;
  constexpr bool SPLITOUT = (MODE >= 2);
  constexpr bool HASBIAS = (MODE >= 1 && MODE <= 3);
  constexpr bool HASBN = (MODE == 3);
  constexpr bool HASRELU = (MODE >= 1 && MODE <= 3);
  __shared__ __align__(16) char ldsA[2 * 7680];
  const int tid = threadIdx.x;
  const int lane = tid & 63;
  const int w = tid >> 6;
  const int rw = w & 1, cwv = w >> 1;
  const int bm = blockIdx.x * 96;
  const int kc = (lane >> 4) & 3;
  const int l15 = lane & 15;

  int aoff[3], bgoff[5];
  #pragma unroll
  for (int fr = 0; fr < 3; fr++) aoff[fr] = (rw * 48 + fr * 16 + l15) * 80 + kc * 16;
  #pragma unroll
  for (int cf = 0; cf < 5; cf++) {
    int col = cwv * 80 + cf * 16 + l15;
    bgoff[cf] = col * 64 + ((kc ^ ((col >> 1) & 3)) << 4);
  }

  f32x4 acc[3][5];
  #pragma unroll
  for (int i = 0; i < 3; i++)
    #pragma unroll
    for (int j = 0; j < 5; j++) { f32x4 z = {0.f, 0.f, 0.f, 0.f}; acc[i][j] = z; }

  f32x4 areg[AIT][2];
  auto issueA = [&](int t) -> bool {
    int pass = 0, tt = t;
    if constexpr (NPASS == 2) { pass = t / (3 * SEGT); tt = t - pass * (3 * SEGT); }
    int seg = tt / SEGT;
    int kk = tt - seg * SEGT;
    const char* __restrict__ base = pass ? A2 : A1;
    #pragma unroll
    for (int it = 0; it < AIT; it++) {
      int s = tid + it * TPB;
      if (s < 384) {
        int row = s >> 2, c = s & 3;
        int r = bm + row; if (r >= M) r = M - 1;
        if constexpr (SRCF32) {
          const char* p = base + (size_t)r * 512 + kk * 128 + c * 32;
          areg[it][0] = *(const f32x4*)p;
          areg[it][1] = *(const f32x4*)(p + 16);
        } else {
          const char* p = base + (size_t)r * 1280 + (seg == 1 ? 640 : 0) + kk * 64 + c * 16;
          areg[it][0] = *(const f32x4*)p;
        }
      }
    }
    return seg == 1;
  };
  auto writeA = [&](int buf, bool lo) {
    #pragma unroll
    for (int it = 0; it < AIT; it++) {
      int s = tid + it * TPB;
      if (s < 384) {
        int row = s >> 2, c = s & 3;
        char* d = &ldsA[buf * 7680 + row * 80 + c * 16];  // 80B pitch: 2-way banks = free
        if constexpr (SRCF32) {
          short8v v;
          #pragma unroll
          for (int j = 0; j < 8; j++) {
            float f = (j < 4) ? areg[it][0][j] : areg[it][1][j - 4];
            unsigned short h = f2bf(f);
            unsigned short o = lo ? f2bf(f - bf2f(h)) : h;
            v[j] = (short)o;
          }
          *(short8v*)d = v;
        } else {
          f32x4 t4 = areg[it][0];
          *(short8v*)d = *(short8v*)&t4;
        }
      }
    }
  };

  short8v bA[5], bB[5];
  auto loadB = [&](int t, short8v (&dst)[5]) {
    const char* __restrict__ src = Wq + (size_t)t * TILEB;
    #pragma unroll
    for (int cf = 0; cf < 5; cf++) dst[cf] = *(const short8v*)(src + bgoff[cf]);
  };

  // one K-step: consume bcur + LDS buf, prefetch A/B for t+1 into nxt buffers
  auto step = [&](int t, int buf, short8v (&bcur)[5], short8v (&bnxt)[5]) {
    bool lo = false;
    if (t + 1 < NT) { lo = issueA(t + 1); loadB(t + 1, bnxt); }
    short8v af0 = *(const short8v*)&ldsA[buf * 7680 + aoff[0]];
    short8v af1 = *(const short8v*)&ldsA[buf * 7680 + aoff[1]];
    short8v af2 = *(const short8v*)&ldsA[buf * 7680 + aoff[2]];
    #pragma unroll
    for (int cf = 0; cf < 5; cf++) {
      acc[0][cf] = __builtin_amdgcn_mfma_f32_16x16x32_bf16(af0, bcur[cf], acc[0][cf], 0, 0, 0);
      acc[1][cf] = __builtin_amdgcn_mfma_f32_16x16x32_bf16(af1, bcur[cf], acc[1][cf], 0, 0, 0);
      acc[2][cf] = __builtin_amdgcn_mfma_f32_16x16x32_bf16(af2, bcur[cf], acc[2][cf], 0, 0, 0);
    }
    if (t + 1 < NT) writeA(buf ^ 1, lo);
    __syncthreads();
  };

  bool plo = issueA(0);
  loadB(0, bA);
  writeA(0, plo);
  __syncthreads();

  for (int t = 0; t < NT; t += 2) {
    step(t, 0, bA, bB);        // even step: LDS buf 0, B in bA, prefetch into bB
    step(t + 1, 1, bB, bA);    // odd step:  LDS buf 1, B in bB, prefetch into bA
  }

  const float bnrs = 0.99999500003749971f;  // 1/sqrt(1+1e-5)
  #pragma unroll
  for (int fr = 0; fr < 3; fr++) {
    int rbase = bm + rw * 48 + fr * 16 + (lane >> 4) * 4;
    #pragma unroll
    for (int cf = 0; cf < 5; cf++) {
      int col = cwv * 80 + cf * 16 + l15;
      float bi = 0.f, sc = 1.f, be = 0.f;
      if constexpr (HASBIAS) bi = bias[col];
      if constexpr (HASBN) { sc = gamma[col] * bnrs; be = beta[col]; }
      #pragma unroll
      for (int rg = 0; rg < 4; rg++) {
        int r = rbase + rg;
        if (r < M) {
          float v = acc[fr][cf][rg];
          if constexpr (HASBIAS) v += bi;
          if constexpr (HASBN) v = v * sc + be;
          if constexpr (HASRELU) v = v > 0.f ? v : 0.f;
          if constexpr (SPLITOUT) {
            unsigned short h = f2bf(v);
            unsigned short g = f2bf(v - bf2f(h));
            unsigned short* o = (unsigned short*)outp;
            o[(size_t)r * 640 + col] = h;
            o[(size_t)r * 640 + 320 + col] = g;
          } else {
            ((float*)outp)[(size_t)r * N + col] = v;
          }
        }
      }
    }
  }
}

// ======================= SAGE mean aggregation: gather HI plane only ============
__global__ __launch_bounds__(256) void sage_agg_split(const unsigned* __restrict__ hp,
    const int* __restrict__ row_off, const int* __restrict__ csr_src,
    unsigned* __restrict__ outp, int n) {
  int node = blockIdx.x * 8 + (threadIdx.x >> 5);
  int lane = threadIdx.x & 31;
  if (node >= n) return;
  int beg = row_off[node], end = row_off[node + 1];
  float s0[5] = {0,0,0,0,0}, s1[5] = {0,0,0,0,0};
  for (int e = beg; e < end; e++) {
    const unsigned* row = hp + (size_t)csr_src[e] * 320;
    #pragma unroll
    for (int k = 0; k < 5; k++) {
      unsigned dh = row[lane + 32 * k];
      s0[k] += bf2f((unsigned short)dh);
      s1[k] += bf2f((unsigned short)(dh >> 16));
    }
  }
  int deg = end - beg;
  float inv = 1.0f / (float)(deg > 0 ? deg : 1);
  unsigned* orow = outp + (size_t)node * 320;
  #pragma unroll
  for (int k = 0; k < 5; k++) {
    float v0 = s0[k] * inv;
    float v1 = s1[k] * inv;
    unsigned short h0 = f2bf(v0), h1 = f2bf(v1);
    unsigned short g0 = f2bf(v0 - bf2f(h0)), g1 = f2bf(v1 - bf2f(h1));
    orow[lane + 32 * k] = (unsigned)h0 | ((unsigned)h1 << 16);
    orow[160 + lane + 32 * k] = (unsigned)g0 | ((unsigned)g1 << 16);
  }
}

// ======================= GAT: attention dots from split planes ==================
__global__ void gat_prep(const unsigned short* __restrict__ xs,
    const float* __restrict__ asrc, const float* __restrict__ adst,
    float* __restrict__ al, float* __restrict__ ar, int n) {
  int idx = blockIdx.x * 256 + threadIdx.x;
  if (idx >= n * HEADS) return;
  int node = idx >> 2, hh = idx & 3;
  const unsigned short* hi = xs + (size_t)node * 640 + hh * 80;
  const unsigned short* lo = hi + 320;
  const f32x4* as4 = (const f32x4*)(asrc + hh * HDIM);
  const f32x4* ad4 = (const f32x4*)(adst + hh * HDIM);
  float sl = 0.f, sr = 0.f;
  #pragma unroll
  for (int d8 = 0; d8 < 10; d8++) {
    short8v vh = *(const short8v*)(hi + d8 * 8);
    short8v vl = *(const short8v*)(lo + d8 * 8);
    f32x4 a0 = as4[2 * d8], a1 = as4[2 * d8 + 1];
    f32x4 b0 = ad4[2 * d8], b1 = ad4[2 * d8 + 1];
    #pragma unroll
    for (int j = 0; j < 4; j++) {
      float v = bf2f((unsigned short)vh[j]) + bf2f((unsigned short)vl[j]);
      sl += v * a0[j]; sr += v * b0[j];
    }
    #pragma unroll
    for (int j = 0; j < 4; j++) {
      float v = bf2f((unsigned short)vh[4 + j]) + bf2f((unsigned short)vl[4 + j]);
      sl += v * a1[j]; sr += v * b1[j];
    }
  }
  al[idx] = sl;
  ar[idx] = sr;
}

// ======================= GAT aggregation: HI-plane gather + softmax + epilogue ==
template<bool F32OUT>
__global__ __launch_bounds__(256) void gat_agg(const unsigned short* __restrict__ hp,
    const int* __restrict__ row_off, const int* __restrict__ csr_src,
    const float* __restrict__ al, const float* __restrict__ ar,
    const float* __restrict__ bias, const float* __restrict__ gamma,
    const float* __restrict__ beta, unsigned short* __restrict__ outS,
    float* __restrict__ outF, int n) {
  int node = (blockIdx.x << 2) + (threadIdx.x >> 6);
  int lane = threadIdx.x & 63;
  if (node >= n) return;
  int beg = row_off[node], end = row_off[node + 1];
  const int hh = lane >> 4;                 // head of this lane (loop-invariant)
  const int posb = hh * 80 + (lane & 15);   // features posb + 16k, k = 0..4

  float arv[4], sh[4];
  f32x4 a4i = *(const f32x4*)(al + (size_t)node * 4);
  #pragma unroll
  for (int h = 0; h < 4; h++) {
    arv[h] = ar[node * 4 + h];
    float v = a4i[h] + arv[h];
    sh[h] = fmaxf(v, NEG_SLOPE * v);        // self-loop score = stabilizing shift
  }
  float den[4] = {1.f, 1.f, 1.f, 1.f};      // self term: exp(0) = 1
  const unsigned short* selfrow = hp + (size_t)node * 640;
  float num[5];
  #pragma unroll
  for (int k = 0; k < 5; k++) {
    int p = posb + 16 * k;
    num[k] = bf2f(selfrow[p]) + bf2f(selfrow[320 + p]);  // exact self feature
  }

  for (int e = beg; e < end; e++) {
    int s = __builtin_amdgcn_readfirstlane(csr_src[e]);
    f32x4 a4 = *(const f32x4*)(al + (size_t)s * 4);
    float ex[4];
    #pragma unroll
    for (int h = 0; h < 4; h++) {
      float v = a4[h] + arv[h];
      v = fmaxf(v, NEG_SLOPE * v);          // leaky_relu
      float r = __expf(v - sh[h]);
      ex[h] = r;
      den[h] += r;
    }
    float exsel = hh < 2 ? (hh == 0 ? ex[0] : ex[1]) : (hh == 2 ? ex[2] : ex[3]);
    const unsigned short* __restrict__ row = hp + (size_t)s * 640;
    #pragma unroll
    for (int k = 0; k < 5; k++) num[k] += exsel * bf2f(row[posb + 16 * k]);
  }

  float dsel = hh < 2 ? (hh == 0 ? den[0] : den[1]) : (hh == 2 ? den[2] : den[3]);
  float dinv = 1.0f / dsel;                 // den >= 1 always
  const float bnrs = 0.99999500003749971f;  // 1/sqrt(1+1e-5)
  #pragma unroll
  for (int k = 0; k < 5; k++) {
    int p = posb + 16 * k;
    float v = num[k] * dinv + bias[p];
    v = v * (gamma[p] * bnrs) + beta[p];
    v = fmaxf(v, 0.f);
    unsigned short h2 = f2bf(v);
    outS[(size_t)node * 640 + p] = h2;
    outS[(size_t)node * 640 + 320 + p] = f2bf(v - bf2f(h2));
    if constexpr (F32OUT) outF[(size_t)node * 320 + p] = v;
  }
}

// ======================= classifier second layer ================================
__global__ void cls2_kernel(const float* __restrict__ tbuf, const float* __restrict__ w2,
                            const float* __restrict__ b2, float* __restrict__ out, int M) {
  int r = blockIdx.x * 256 + threadIdx.x;
  if (r >= M) return;
  const f32x4* row = (const f32x4*)(tbuf + (size_t)r * 160);
  float a0 = b2[0], a1 = b2[1];
  #pragma unroll
  for (int d4 = 0; d4 < 40; d4++) {
    f32x4 v = row[d4];
    #pragma unroll
    for (int j = 0; j < 4; j++) {
      int d = d4 * 4 + j;
      a0 += v[j] * w2[2 * d];
      a1 += v[j] * w2[2 * d + 1];
    }
  }
  out[2 * r] = a0;
  out[2 * r + 1] = a1;
}

// ======================= launch =======================
extern "C" void kernel_launch(void* const* d_in, const int* in_sizes, int n_in,
                              void* d_out, int out_size, void* d_ws, size_t ws_size,
                              hipStream_t stream) {
  const float* x    = (const float*)d_in[0];
  const int*   ei   = (const int*)d_in[1];
  const float* w_in = (const float*)d_in[2];
  const float* b_in = (const float*)d_in[3];
  const float* s0wl = (const float*)d_in[4];
  const float* s0bl = (const float*)d_in[5];
  const float* s0wr = (const float*)d_in[6];
  const float* g1w  = (const float*)d_in[7];
  const float* g1as = (const float*)d_in[8];
  const float* g1ad = (const float*)d_in[9];
  const float* g1b  = (const float*)d_in[10];
  const float* s2wl = (const float*)d_in[11];
  const float* s2bl = (const float*)d_in[12];
  const float* s2wr = (const float*)d_in[13];
  const float* g3w  = (const float*)d_in[14];
  const float* g3as = (const float*)d_in[15];
  const float* g3ad = (const float*)d_in[16];
  const float* g3b  = (const float*)d_in[17];
  const float* bng  = (const float*)d_in[18];
  const float* bnb  = (const float*)d_in[19];
  const float* cw1  = (const float*)d_in[20];
  const float* cb1  = (const float*)d_in[21];
  const float* cw2  = (const float*)d_in[22];
  const float* cb2  = (const float*)d_in[23];

  char* ws = (char*)d_ws;
  size_t off = 0;
  auto alloc = [&](size_t b) {
    void* p = (void*)(ws + off);
    off += (b + 255) & ~(size_t)255;
    return p;
  };
  const size_t SB = (size_t)MN * 1280;        // one split-plane matrix [M][640] bf16
  char* S0 = (char*)alloc(SB);
  char* S1 = (char*)alloc(SB);
  char* S2 = (char*)alloc(SB);
  char* WQ = (char*)alloc(4239360);
  float* al      = (float*)alloc((size_t)MN * HEADS * 4);
  float* ar      = (float*)alloc((size_t)MN * HEADS * 4);
  int*   row_off = (int*)alloc((size_t)(MN + 1) * 4);
  int*   hist    = (int*)alloc((size_t)MN * 4);
  int*   curw    = (int*)alloc((size_t)MN * 4);
  int*   csr     = (int*)alloc((size_t)EN * 4);

  float* outp = (float*)d_out;
  float* emb  = outp + (size_t)MN * 2;        // [M,320] fp32 slot; doubles as xh1 split scratch

  const int* srcp = ei;
  const int* dstp = ei + EN;

  // CSR
  hipMemsetAsync(hist, 0, MN * 4, stream);
  hipMemsetAsync(curw, 0, MN * 4, stream);
  hist_kernel<<<(EN + 255) / 256, 256, 0, stream>>>(dstp, hist, EN);
  scan_kernel<<<1, 1024, 0, stream>>>(hist, row_off, MN);
  scatter_kernel<<<(EN + 255) / 256, 256, 0, stream>>>(srcp, dstp, row_off, curw, csr, EN);

  // weight prep (stacked+transposed+split+swizzled): tile = Nsz*64 bytes
  char* wq_in = WQ + 0;        // 12 tiles of 20480
  char* wq_s0 = WQ + 245760;   // 60 tiles (wl 30 | wr 30)
  char* wq_g1 = WQ + 1474560;  // 30
  char* wq_s2 = WQ + 2088960;  // 60
  char* wq_g3 = WQ + 3317760;  // 30
  char* wq_cl = WQ + 3932160;  // 30 tiles of 10240
  int tot = 12 * 320 * 32;
  wprep<<<(tot + 255) / 256, 256, 0, stream>>>(w_in, (unsigned short*)wq_in, 128, 320, tot);
  tot = 30 * 320 * 32;
  wprep<<<(tot + 255) / 256, 256, 0, stream>>>(s0wl, (unsigned short*)wq_s0, 320, 320, tot);
  wprep<<<(tot + 255) / 256, 256, 0, stream>>>(s0wr, (unsigned short*)(wq_s0 + 614400), 320, 320, tot);
  wprep<<<(tot + 255) / 256, 256, 0, stream>>>(g1w,  (unsigned short*)wq_g1, 320, 320, tot);
  wprep<<<(tot + 255) / 256, 256, 0, stream>>>(s2wl, (unsigned short*)wq_s2, 320, 320, tot);
  wprep<<<(tot + 255) / 256, 256, 0, stream>>>(s2wr, (unsigned short*)(wq_s2 + 614400), 320, 320, tot);
  wprep<<<(tot + 255) / 256, 256, 0, stream>>>(g3w,  (unsigned short*)wq_g3, 320, 320, tot);
  tot = 30 * 160 * 32;
  wprep<<<(tot + 255) / 256, 256, 0, stream>>>(cw1, (unsigned short*)wq_cl, 320, 160, tot);

  const int gx = (MN + 95) / 96;   // 521
  const int ga = (MN + 3) / 4;
  const int gs = (MN + 7) / 8;

  // h0 = relu(x@w_in + b_in)  -> split S0
  mfma_gemm<4, true, 4, 1, 2><<<gx, 512, 0, stream>>>(
      (const char*)x, nullptr, wq_in, b_in, nullptr, nullptr, S0, MN);
  // SAGE0: hi-plane mean(S0) -> split S1 ; h1 = relu(BN0(...)) -> split S2
  sage_agg_split<<<gs, 256, 0, stream>>>((const unsigned*)S0, row_off, csr, (unsigned*)S1, MN);
  mfma_gemm<4, false, 10, 2, 3><<<gx, 512, 0, stream>>>(
      S1, S0, wq_s0, s0bl, bng, bnb, S2, MN);
  // GAT1: xh1 = S2@g1w -> SPLIT into emb region ; attn ; result split -> S0
  mfma_gemm<4, false, 10, 1, 4><<<gx, 512, 0, stream>>>(
      S2, nullptr, wq_g1, nullptr, nullptr, nullptr, emb, MN);
  gat_prep<<<(MN * HEADS + 255) / 256, 256, 0, stream>>>(
      (const unsigned short*)emb, g1as, g1ad, al, ar, MN);
  gat_agg<false><<<ga, 256, 0, stream>>>(
      (const unsigned short*)emb, row_off, csr, al, ar, g1b, bng + 320, bnb + 320,
      (unsigned short*)S0, nullptr, MN);
  // SAGE2: hi-plane mean(S0) -> split S1 ; h3 -> split S2
  sage_agg_split<<<gs, 256, 0, stream>>>((const unsigned*)S0, row_off, csr, (unsigned*)S1, MN);
  mfma_gemm<4, false, 10, 2, 3><<<gx, 512, 0, stream>>>(
      S1, S0, wq_s2, s2bl, bng + 640, bnb + 640, S2, MN);
  // GAT3: xh3 = S2@g3w -> SPLIT into S0 ; attn ; embeddings fp32 -> emb, split -> S1
  mfma_gemm<4, false, 10, 1, 4><<<gx, 512, 0, stream>>>(
      S2, nullptr, wq_g3, nullptr, nullptr, nullptr, S0, MN);
  gat_prep<<<(MN * HEADS + 255) / 256, 256, 0, stream>>>(
      (const unsigned short*)S0, g3as, g3ad, al, ar, MN);
  gat_agg<true><<<ga, 256, 0, stream>>>(
      (const unsigned short*)S0, row_off, csr, al, ar, g3b, bng + 960, bnb + 960,
      (unsigned short*)S1, emb, MN);
  // classifier
  mfma_gemm<2, false, 10, 1, 1><<<gx, 256, 0, stream>>>(
      S1, nullptr, wq_cl, cb1, nullptr, nullptr, S2, MN);
  cls2_kernel<<<(MN + 255) / 256, 256, 0, stream>>>((const float*)S2, cw2, cb2, outp, MN);
}